// Round 3
// baseline (1968.987 us; speedup 1.0000x reference)
//
#include <hip/hip_runtime.h>
#include <hip/hip_bf16.h>

// Problem constants (B=4, S=2048, D=2048, FF=8192, E=2)
#define T_TOK   8192
#define D_DIM   2048
#define FF_DIM  8192
#define PADT    8448    // 66*128 >= worst-case padded total (8320)

// ctrl ints: [0]=count0 [1]=count1 [2]=cursor0 [3]=cursor1 [4]=base1 [5]=padded_total
#define C_CNT0 0
#define C_CNT1 1
#define C_CUR0 2
#define C_BASE1 4
#define C_PTOT 5

typedef __attribute__((ext_vector_type(4))) float f32x4;
typedef __attribute__((ext_vector_type(8))) short short8;

__device__ __forceinline__ unsigned short f2bf(float f) {
  union { __hip_bfloat16 b; unsigned short u; } cv;
  cv.b = __float2bfloat16(f);
  return cv.u;
}

__device__ __forceinline__ void gload16(const void* g, void* l) {
  __builtin_amdgcn_global_load_lds(
      (const __attribute__((address_space(1))) void*)g,
      (__attribute__((address_space(3))) void*)l,
      16, 0, 0);
}

// ---------------- weight fp32 -> bf16 conversion ----------------
__global__ __launch_bounds__(256) void cvt_kernel(const float4* __restrict__ src,
                                                  ushort4* __restrict__ dst, int n4) {
  int i = blockIdx.x * blockDim.x + threadIdx.x;
  if (i < n4) {
    float4 v = src[i];
    dst[i] = make_ushort4(f2bf(v.x), f2bf(v.y), f2bf(v.z), f2bf(v.w));
  }
}

// ---------------- init: zero ctrl + perm = -1 ----------------
__global__ __launch_bounds__(256) void init_kernel(int* __restrict__ ctrl,
                                                   int* __restrict__ perm) {
  int i = blockIdx.x * blockDim.x + threadIdx.x;
  if (i < 8) ctrl[i] = 0;
  if (i < PADT) perm[i] = -1;
}

// ---------------- router: logits, argmax, top-1 weight ----------------
__global__ __launch_bounds__(256) void router_kernel(const float* __restrict__ x,
                                                     const float* __restrict__ gw,
                                                     int* __restrict__ sel,
                                                     float* __restrict__ topw,
                                                     int* __restrict__ ctrl) {
  const int w = threadIdx.x >> 6, l = threadIdx.x & 63;
  const int t = blockIdx.x * 4 + w;
  const float4* xr = (const float4*)(x + (size_t)t * D_DIM);
  const float4* g0 = (const float4*)gw;
  const float4* g1 = (const float4*)(gw + D_DIM);
  float d0 = 0.f, d1 = 0.f;
#pragma unroll
  for (int i = 0; i < 8; i++) {
    float4 v = xr[i * 64 + l];
    float4 a = g0[i * 64 + l];
    float4 b = g1[i * 64 + l];
    d0 += v.x * a.x + v.y * a.y + v.z * a.z + v.w * a.w;
    d1 += v.x * b.x + v.y * b.y + v.z * b.z + v.w * b.w;
  }
#pragma unroll
  for (int s = 32; s; s >>= 1) {
    d0 += __shfl_xor(d0, s);
    d1 += __shfl_xor(d1, s);
  }
  if (l == 0) {
    int e = (d1 > d0) ? 1 : 0;                 // jnp.argmax tie -> first index
    float dd = fabsf(d1 - d0);
    sel[t] = e;
    topw[t] = 1.f / (1.f + expf(-dd));         // softmax prob of winner (E=2)
    atomicAdd(&ctrl[e], 1);
  }
}

// ---------------- setup: segment bases (1 thread) ----------------
__global__ void setup_kernel(int* __restrict__ ctrl) {
  if (threadIdx.x == 0) {
    int c0 = ctrl[C_CNT0], c1 = ctrl[C_CNT1];
    int b1 = ((c0 + 127) >> 7) << 7;
    ctrl[C_BASE1] = b1;
    ctrl[C_PTOT] = b1 + (((c1 + 127) >> 7) << 7);
  }
}

// ---------------- scatter: fill permutation ----------------
__global__ __launch_bounds__(256) void scatter_kernel(const int* __restrict__ sel,
                                                      int* __restrict__ ctrl,
                                                      int* __restrict__ perm) {
  int t = blockIdx.x * blockDim.x + threadIdx.x;
  int e = sel[t];
  int base = e ? ctrl[C_BASE1] : 0;
  int pos = base + atomicAdd(&ctrl[C_CUR0 + e], 1);
  perm[pos] = t;
}

// ---------------- gather: x -> bf16 permuted activations ----------------
__global__ __launch_bounds__(256) void gather_kernel(const float* __restrict__ x,
                                                     const int* __restrict__ perm,
                                                     const float* __restrict__ topw,
                                                     ushort* __restrict__ Xg,
                                                     float* __restrict__ twg) {
  const int w = threadIdx.x >> 6, l = threadIdx.x & 63;
  const int pos = blockIdx.x * 4 + w;
  const int t = perm[pos];
  if (l == 0) twg[pos] = (t >= 0) ? topw[t] : 0.f;
  ushort4* dst = (ushort4*)(Xg + (size_t)pos * D_DIM);
  if (t >= 0) {
    const float4* src = (const float4*)(x + (size_t)t * D_DIM);
#pragma unroll
    for (int i = 0; i < 8; i++) {
      float4 v = src[i * 64 + l];
      dst[i * 64 + l] = make_ushort4(f2bf(v.x), f2bf(v.y), f2bf(v.z), f2bf(v.w));
    }
  } else {
    ushort4 z = make_ushort4(0, 0, 0, 0);
#pragma unroll
    for (int i = 0; i < 8; i++) dst[i * 64 + l] = z;
  }
}

// ---------------- GEMM1: H = silu(Xg @ Wg^T) * (Xg @ Wu^T), bf16 out ----------------
// 128x128 tile, BK=32, 4 waves (2x2); each wave 64x64 per matrix = 4x4 frags 16x16x32.
// m97-proven structure: global_load_lds width=16 staging, 2 barriers per K-step.
__global__ __launch_bounds__(256, 2) void gemm1_kernel(const ushort* __restrict__ Xg,
                                                       const ushort* __restrict__ Wg,
                                                       const ushort* __restrict__ Wu,
                                                       ushort* __restrict__ H,
                                                       const int* __restrict__ ctrl) {
  __shared__ ushort As[128 * 32];
  __shared__ ushort Bgs[128 * 32];
  __shared__ ushort Bus[128 * 32];

  const int row0 = blockIdx.x * 128;
  if (row0 >= ctrl[C_PTOT]) return;          // block-uniform early out
  const int e = (row0 >= ctrl[C_BASE1]) ? 1 : 0;
  const int tn = blockIdx.y;

  const int tid = threadIdx.x;
  const int w = tid >> 6, l = tid & 63;
  const int wr = w >> 1, wc = w & 1;

  const ushort* A  = Xg + (size_t)row0 * D_DIM;
  const ushort* Bg = Wg + ((size_t)e * FF_DIM + (size_t)tn * 128) * D_DIM;
  const ushort* Bu = Wu + ((size_t)e * FF_DIM + (size_t)tn * 128) * D_DIM;

  // staging: chunk q covers rows q*16..q*16+15 of [128][32] (1024B);
  // lane l -> row q*16 + l/4, col (l&3)*8 ushorts == LDS base + l*16B (linear dest).
  const int q0 = w * 2, q1 = q0 + 1;
  const int scol = (l & 3) * 8;
  const ushort* a0  = A  + (size_t)(q0 * 16 + (l >> 2)) * D_DIM + scol;
  const ushort* a1  = A  + (size_t)(q1 * 16 + (l >> 2)) * D_DIM + scol;
  const ushort* bg0 = Bg + (size_t)(q0 * 16 + (l >> 2)) * D_DIM + scol;
  const ushort* bg1 = Bg + (size_t)(q1 * 16 + (l >> 2)) * D_DIM + scol;
  const ushort* bu0 = Bu + (size_t)(q0 * 16 + (l >> 2)) * D_DIM + scol;
  const ushort* bu1 = Bu + (size_t)(q1 * 16 + (l >> 2)) * D_DIM + scol;
  ushort* lA0 = &As [q0 * 512];
  ushort* lA1 = &As [q1 * 512];
  ushort* lG0 = &Bgs[q0 * 512];
  ushort* lG1 = &Bgs[q1 * 512];
  ushort* lU0 = &Bus[q0 * 512];
  ushort* lU1 = &Bus[q1 * 512];

  f32x4 accg[4][4] = {};
  f32x4 accu[4][4] = {};

  const int fr = l & 15, fk = (l >> 4) * 8;   // A/B frag: row = lane&15, k = (lane>>4)*8

  for (int k0 = 0; k0 < D_DIM; k0 += 32) {
    gload16(a0 + k0, lA0);
    gload16(a1 + k0, lA1);
    gload16(bg0 + k0, lG0);
    gload16(bg1 + k0, lG1);
    gload16(bu0 + k0, lU0);
    gload16(bu1 + k0, lU1);
    __syncthreads();
    short8 a[4], bg[4], bu[4];
#pragma unroll
    for (int i = 0; i < 4; i++) a[i]  = *(const short8*)&As [(wr * 64 + i * 16 + fr) * 32 + fk];
#pragma unroll
    for (int j = 0; j < 4; j++) bg[j] = *(const short8*)&Bgs[(wc * 64 + j * 16 + fr) * 32 + fk];
#pragma unroll
    for (int j = 0; j < 4; j++) bu[j] = *(const short8*)&Bus[(wc * 64 + j * 16 + fr) * 32 + fk];
#pragma unroll
    for (int i = 0; i < 4; i++)
#pragma unroll
      for (int j = 0; j < 4; j++) {
        accg[i][j] = __builtin_amdgcn_mfma_f32_16x16x32_bf16(a[i], bg[j], accg[i][j], 0, 0, 0);
        accu[i][j] = __builtin_amdgcn_mfma_f32_16x16x32_bf16(a[i], bu[j], accu[i][j], 0, 0, 0);
      }
    __syncthreads();
  }

  const int m4 = (l >> 4) * 4;   // C/D: col = lane&15, row = (lane>>4)*4 + reg (m89-verified)
#pragma unroll
  for (int i = 0; i < 4; i++) {
#pragma unroll
    for (int r = 0; r < 4; r++) {
      size_t hrow = (size_t)(row0 + wr * 64 + i * 16 + m4 + r) * FF_DIM + (size_t)tn * 128 + wc * 64;
#pragma unroll
      for (int j = 0; j < 4; j++) {
        float g = accg[i][j][r], u = accu[i][j][r];
        float h = (g / (1.f + __expf(-g))) * u;   // silu(g)*u
        H[hrow + j * 16 + fr] = f2bf(h);
      }
    }
  }
}

// ---------------- GEMM2: out[tok] = (H @ Wd^T) * topw, fp32 scatter ----------------
__global__ __launch_bounds__(256, 2) void gemm2_kernel(const ushort* __restrict__ H,
                                                       const ushort* __restrict__ Wd,
                                                       const int* __restrict__ perm,
                                                       const float* __restrict__ twg,
                                                       float* __restrict__ out,
                                                       const int* __restrict__ ctrl) {
  __shared__ ushort As[128 * 32];
  __shared__ ushort Bs[128 * 32];

  const int row0 = blockIdx.x * 128;
  if (row0 >= ctrl[C_PTOT]) return;
  const int e = (row0 >= ctrl[C_BASE1]) ? 1 : 0;
  const int tn = blockIdx.y;

  const int tid = threadIdx.x;
  const int w = tid >> 6, l = tid & 63;
  const int wr = w >> 1, wc = w & 1;

  const ushort* A = H  + (size_t)row0 * FF_DIM;
  const ushort* B = Wd + ((size_t)e * D_DIM + (size_t)tn * 128) * FF_DIM;

  const int q0 = w * 2, q1 = q0 + 1;
  const int scol = (l & 3) * 8;
  const ushort* a0 = A + (size_t)(q0 * 16 + (l >> 2)) * FF_DIM + scol;
  const ushort* a1 = A + (size_t)(q1 * 16 + (l >> 2)) * FF_DIM + scol;
  const ushort* b0 = B + (size_t)(q0 * 16 + (l >> 2)) * FF_DIM + scol;
  const ushort* b1 = B + (size_t)(q1 * 16 + (l >> 2)) * FF_DIM + scol;
  ushort* lA0 = &As[q0 * 512];
  ushort* lA1 = &As[q1 * 512];
  ushort* lB0 = &Bs[q0 * 512];
  ushort* lB1 = &Bs[q1 * 512];

  f32x4 acc[4][4] = {};
  const int fr = l & 15, fk = (l >> 4) * 8;

  for (int k0 = 0; k0 < FF_DIM; k0 += 32) {
    gload16(a0 + k0, lA0);
    gload16(a1 + k0, lA1);
    gload16(b0 + k0, lB0);
    gload16(b1 + k0, lB1);
    __syncthreads();
    short8 a[4], b[4];
#pragma unroll
    for (int i = 0; i < 4; i++) a[i] = *(const short8*)&As[(wr * 64 + i * 16 + fr) * 32 + fk];
#pragma unroll
    for (int j = 0; j < 4; j++) b[j] = *(const short8*)&Bs[(wc * 64 + j * 16 + fr) * 32 + fk];
#pragma unroll
    for (int i = 0; i < 4; i++)
#pragma unroll
      for (int j = 0; j < 4; j++)
        acc[i][j] = __builtin_amdgcn_mfma_f32_16x16x32_bf16(a[i], b[j], acc[i][j], 0, 0, 0);
    __syncthreads();
  }

  const int m4 = (l >> 4) * 4;
#pragma unroll
  for (int i = 0; i < 4; i++) {
#pragma unroll
    for (int r = 0; r < 4; r++) {
      int prow = row0 + wr * 64 + i * 16 + m4 + r;
      int tok = perm[prow];
      if (tok < 0) continue;               // padding row
      float tw = twg[prow];
      float* orow = out + (size_t)tok * D_DIM + (size_t)tn * 128 + wc * 64;
#pragma unroll
      for (int j = 0; j < 4; j++) orow[j * 16 + fr] = acc[i][j][r] * tw;
    }
  }
}

// ---------------- launch ----------------
extern "C" void kernel_launch(void* const* d_in, const int* in_sizes, int n_in,
                              void* d_out, int out_size, void* d_ws, size_t ws_size,
                              hipStream_t stream) {
  const float* x  = (const float*)d_in[0];   // [B,S,D] fp32
  const float* gw = (const float*)d_in[1];   // [E,D]
  const float* wg = (const float*)d_in[2];   // [E,FF,D]
  const float* wu = (const float*)d_in[3];   // [E,FF,D]
  const float* wd = (const float*)d_in[4];   // [E,D,FF]
  float* out = (float*)d_out;

  char* ws = (char*)d_ws;
  size_t off = 0;
  auto alloc = [&](size_t bytes) -> void* {
    void* p = ws + off;
    off += (bytes + 255) & ~(size_t)255;
    return p;
  };
  const size_t WELEM = (size_t)2 * FF_DIM * D_DIM;  // 33,554,432 elems per weight tensor
  ushort* Wg_b = (ushort*)alloc(WELEM * 2);
  ushort* Wu_b = (ushort*)alloc(WELEM * 2);
  ushort* Wd_b = (ushort*)alloc(WELEM * 2);
  ushort* Xg   = (ushort*)alloc((size_t)PADT * D_DIM * 2);
  ushort* Hbuf = (ushort*)alloc((size_t)PADT * FF_DIM * 2);
  int*   sel  = (int*)alloc(T_TOK * 4);
  float* topw = (float*)alloc(T_TOK * 4);
  int*   perm = (int*)alloc(PADT * 4);
  float* twg  = (float*)alloc(PADT * 4);
  int*   ctrl = (int*)alloc(256);
  (void)ws_size; (void)in_sizes; (void)n_in; (void)out_size;

  const int n4 = (int)(WELEM / 4);            // 8,388,608 float4 per weight
  cvt_kernel<<<n4 / 256, 256, 0, stream>>>((const float4*)wg, (ushort4*)Wg_b, n4);
  cvt_kernel<<<n4 / 256, 256, 0, stream>>>((const float4*)wu, (ushort4*)Wu_b, n4);
  cvt_kernel<<<n4 / 256, 256, 0, stream>>>((const float4*)wd, (ushort4*)Wd_b, n4);

  init_kernel<<<(PADT + 255) / 256, 256, 0, stream>>>(ctrl, perm);
  router_kernel<<<T_TOK / 4, 256, 0, stream>>>(x, gw, sel, topw, ctrl);
  setup_kernel<<<1, 64, 0, stream>>>(ctrl);
  scatter_kernel<<<T_TOK / 256, 256, 0, stream>>>(sel, ctrl, perm);
  gather_kernel<<<PADT / 4, 256, 0, stream>>>(x, perm, topw, Xg, twg);

  dim3 g1(PADT / 128, FF_DIM / 128);   // 66 x 64
  gemm1_kernel<<<g1, 256, 0, stream>>>(Xg, Wg_b, Wu_b, Hbuf, ctrl);
  dim3 g2(PADT / 128, D_DIM / 128);    // 66 x 16
  gemm2_kernel<<<g2, 256, 0, stream>>>(Hbuf, Wd_b, perm, twg, out, ctrl);
}

// Round 6
// 1649.468 us; speedup vs baseline: 1.1937x; 1.1937x over previous
//
#include <hip/hip_runtime.h>
#include <hip/hip_bf16.h>

// Problem constants (B=4, S=2048, D=2048, FF=8192, E=2)
#define T_TOK   8192
#define D_DIM   2048
#define FF_DIM  8192
#define PADT    8448      // 33*256 >= worst-case 256-padded total (8448)
#define NMT     33        // M-tiles of 256
#define G1_GRID (NMT*64)  // 2112 (FF gate+up interleaved: 16384/256)
#define G2_GRID (NMT*8)   // 264  (D: 2048/256)
#define NT1     64        // K-tiles gemm1: 2048/32
#define NT2     256       // K-tiles gemm2: 8192/32

// ctrl ints: [0]=count0 [1]=count1 [2]=cursor0 [3]=cursor1 [4]=base1 [5]=padded_total
#define C_CNT0 0
#define C_CNT1 1
#define C_CUR0 2
#define C_BASE1 4
#define C_PTOT 5

typedef __attribute__((ext_vector_type(4))) float f32x4;
typedef __attribute__((ext_vector_type(8))) short short8;

__device__ __forceinline__ unsigned short f2bf(float f) {
  union { __hip_bfloat16 b; unsigned short u; } cv;
  cv.b = __float2bfloat16(f);
  return cv.u;
}

__device__ __forceinline__ void gload16(const void* g, void* l) {
  __builtin_amdgcn_global_load_lds(
      (const __attribute__((address_space(1))) void*)g,
      (__attribute__((address_space(3))) void*)l,
      16, 0, 0);
}

// ---------------- weight fp32 -> bf16 conversion (3 tensors, 1 launch) ----------------
__global__ __launch_bounds__(256) void cvt3_kernel(const float4* __restrict__ sa,
                                                   const float4* __restrict__ sb,
                                                   const float4* __restrict__ sc,
                                                   ushort4* __restrict__ da,
                                                   ushort4* __restrict__ db,
                                                   ushort4* __restrict__ dc, int n4) {
  const int stride = gridDim.x * blockDim.x;
  for (int i = blockIdx.x * blockDim.x + threadIdx.x; i < n4; i += stride) {
    float4 v = sa[i];
    da[i] = make_ushort4(f2bf(v.x), f2bf(v.y), f2bf(v.z), f2bf(v.w));
    v = sb[i];
    db[i] = make_ushort4(f2bf(v.x), f2bf(v.y), f2bf(v.z), f2bf(v.w));
    v = sc[i];
    dc[i] = make_ushort4(f2bf(v.x), f2bf(v.y), f2bf(v.z), f2bf(v.w));
  }
}

// ---------------- init: zero ctrl + perm = -1 ----------------
__global__ __launch_bounds__(256) void init_kernel(int* __restrict__ ctrl,
                                                   int* __restrict__ perm) {
  int i = blockIdx.x * blockDim.x + threadIdx.x;
  if (i < 8) ctrl[i] = 0;
  if (i < PADT) perm[i] = -1;
}

// ---------------- router ----------------
__global__ __launch_bounds__(256) void router_kernel(const float* __restrict__ x,
                                                     const float* __restrict__ gw,
                                                     int* __restrict__ sel,
                                                     float* __restrict__ topw,
                                                     int* __restrict__ ctrl) {
  const int w = threadIdx.x >> 6, l = threadIdx.x & 63;
  const int t = blockIdx.x * 4 + w;
  const float4* xr = (const float4*)(x + (size_t)t * D_DIM);
  const float4* g0 = (const float4*)gw;
  const float4* g1 = (const float4*)(gw + D_DIM);
  float d0 = 0.f, d1 = 0.f;
#pragma unroll
  for (int i = 0; i < 8; i++) {
    float4 v = xr[i * 64 + l];
    float4 a = g0[i * 64 + l];
    float4 b = g1[i * 64 + l];
    d0 += v.x * a.x + v.y * a.y + v.z * a.z + v.w * a.w;
    d1 += v.x * b.x + v.y * b.y + v.z * b.z + v.w * b.w;
  }
#pragma unroll
  for (int s = 32; s; s >>= 1) {
    d0 += __shfl_xor(d0, s);
    d1 += __shfl_xor(d1, s);
  }
  if (l == 0) {
    int e = (d1 > d0) ? 1 : 0;                 // jnp.argmax tie -> first index
    float dd = fabsf(d1 - d0);
    sel[t] = e;
    topw[t] = 1.f / (1.f + expf(-dd));         // softmax prob of winner (E=2)
    atomicAdd(&ctrl[e], 1);
  }
}

// ---------------- setup: 256-aligned segment bases ----------------
__global__ void setup_kernel(int* __restrict__ ctrl) {
  if (threadIdx.x == 0) {
    int c0 = ctrl[C_CNT0], c1 = ctrl[C_CNT1];
    int b1 = ((c0 + 255) >> 8) << 8;
    ctrl[C_BASE1] = b1;
    ctrl[C_PTOT] = b1 + (((c1 + 255) >> 8) << 8);
  }
}

// ---------------- scatter ----------------
__global__ __launch_bounds__(256) void scatter_kernel(const int* __restrict__ sel,
                                                      int* __restrict__ ctrl,
                                                      int* __restrict__ perm) {
  int t = blockIdx.x * blockDim.x + threadIdx.x;
  int e = sel[t];
  int base = e ? ctrl[C_BASE1] : 0;
  int pos = base + atomicAdd(&ctrl[C_CUR0 + e], 1);
  perm[pos] = t;
}

// ---------------- gather: x -> bf16 permuted activations ----------------
__global__ __launch_bounds__(256) void gather_kernel(const float* __restrict__ x,
                                                     const int* __restrict__ perm,
                                                     const float* __restrict__ topw,
                                                     ushort* __restrict__ Xg,
                                                     float* __restrict__ twg) {
  const int w = threadIdx.x >> 6, l = threadIdx.x & 63;
  const int pos = blockIdx.x * 4 + w;
  const int t = perm[pos];
  if (l == 0) twg[pos] = (t >= 0) ? topw[t] : 0.f;
  ushort4* dst = (ushort4*)(Xg + (size_t)pos * D_DIM);
  if (t >= 0) {
    const float4* src = (const float4*)(x + (size_t)t * D_DIM);
#pragma unroll
    for (int i = 0; i < 8; i++) {
      float4 v = src[i * 64 + l];
      dst[i * 64 + l] = make_ushort4(f2bf(v.x), f2bf(v.y), f2bf(v.z), f2bf(v.w));
    }
  } else {
    ushort4 z = make_ushort4(0, 0, 0, 0);
#pragma unroll
    for (int i = 0; i < 8; i++) dst[i * 64 + l] = z;
  }
}

// =====================================================================
// 256x256 GEMM core, BK=32, 8 waves (2M x 4N), triple-buffered LDS.
// Counted wait: each wave issues 4 global_load_lds per STAGE; at tile t
// one staged tile (t+1) may stay in flight -> s_waitcnt vmcnt(4) (NOT 8;
// v3's vmcnt(8) was a no-op wait -> read un-landed LDS -> absmax 38).
// Single raw s_barrier per iter is race-free with TRIPLE buffering:
// reads of buf (t-1)%3 complete before MFMA issue (lgkmcnt), which
// precedes barrier t, which precedes any wave's STAGE into that buf.
// Combined LDS tile [256 rows][64 cols bf16]: chunks 0-3 = A (k 0..31),
// chunks 4-7 = B (k 0..31). Chunk swizzle: phys = logical ^ (row&7);
// store side applies it by pre-swizzling the per-lane GLOBAL source
// (LDS dest stays linear), read side XORs the chunk in aoff/boff.
// =====================================================================

// ---------------- GEMM1: H = silu(Xg@Wg^T) * (Xg@Wu^T), bf16 out ----------------
// B = 256 logical cols interleaving gate/up at 16-col granularity:
// row r of B-tile: matrix = (r>>4)&1 (0=gate,1=up), ff = tn*128 + ((r>>5)<<4) + (r&15).
// Per wave, B-frags j=0..3 alternate gate,up,gate,up with matching ff pairs,
// so silu(g)*u is computed entirely in-register.
__global__ __launch_bounds__(512, 2) void gemm1_kernel(const ushort* __restrict__ Xg,
                                                       const ushort* __restrict__ Wg,
                                                       const ushort* __restrict__ Wu,
                                                       ushort* __restrict__ H,
                                                       const int* __restrict__ ctrl) {
  __shared__ ushort lds[3 * 16384];   // 3 x 32 KB
  const int ptot = ctrl[C_PTOT];
  const int bid = blockIdx.x;
  const int swz = (bid & 7) * (G1_GRID / 8) + (bid >> 3);   // XCD-contiguous chunks
  const int tn = swz / NMT, bx = swz % NMT;
  const int row0 = bx * 256;
  if (row0 >= ptot) return;
  const int e = (row0 >= ctrl[C_BASE1]) ? 1 : 0;

  const int tid = threadIdx.x, w = tid >> 6, l = tid & 63;
  const int wr = w >> 2, wc = w & 3;          // 2M x 4N wave grid
  const int fr = l & 15, kg = l >> 4;

  // --- staging source pointers (pre-swizzled global, linear LDS dest) ---
  auto srcptr = [&](int li) -> const ushort* {
    int o = li * 8192 + w * 1024 + l * 16;    // physical byte offset in tile
    int row = o >> 7, pc = (o >> 4) & 7;
    int lc = pc ^ (row & 7);                  // logical chunk (involution)
    if (lc < 4)                               // A region
      return Xg + (size_t)(row0 + row) * D_DIM + lc * 8;
    int mat = (row >> 4) & 1;                 // B region: gate/up interleave
    int ff = tn * 128 + ((row >> 5) << 4) + (row & 15);
    return (mat ? Wu : Wg) + ((size_t)e * FF_DIM + ff) * D_DIM + (lc - 4) * 8;
  };
  const ushort* s0 = srcptr(0);
  const ushort* s1 = srcptr(1);
  const ushort* s2 = srcptr(2);
  const ushort* s3 = srcptr(3);

  auto STAGE = [&](int buf) {
    ushort* db = lds + buf * 16384 + (w << 9);   // wave-uniform dest base
    gload16(s0, db);          s0 += 32;
    gload16(s1, db + 4096);   s1 += 32;
    gload16(s2, db + 8192);   s2 += 32;
    gload16(s3, db + 12288);  s3 += 32;
  };

  // --- fragment read offsets (swizzled) ---
  const int aoff = (wr * 128 + fr) * 128 + ((kg ^ (fr & 7)) << 4);
  const int boff = (wc * 64 + fr) * 128 + (((4 ^ kg) ^ (fr & 7)) << 4);

  f32x4 acc[8][4] = {};

  STAGE(0);
  STAGE(1);
  int sbuf = 2, cbuf = 0;
  for (int t = 0; t < NT1; ++t) {
    if (t < NT1 - 1) asm volatile("s_waitcnt vmcnt(4)" ::: "memory");
    else             asm volatile("s_waitcnt vmcnt(0)" ::: "memory");
    __builtin_amdgcn_s_barrier();
    asm volatile("" ::: "memory");
    if (t + 2 < NT1) {
      STAGE(sbuf);
      sbuf = (sbuf == 2) ? 0 : sbuf + 1;
    }
    const char* Lb = (const char*)lds + cbuf * 32768;
    cbuf = (cbuf == 2) ? 0 : cbuf + 1;
    short8 bfrag[4], afrag[8];
#pragma unroll
    for (int j = 0; j < 4; j++) bfrag[j] = *(const short8*)(Lb + boff + j * 2048);
#pragma unroll
    for (int i = 0; i < 8; i++) afrag[i] = *(const short8*)(Lb + aoff + i * 2048);
    __builtin_amdgcn_s_setprio(1);
#pragma unroll
    for (int i = 0; i < 8; i++)
#pragma unroll
      for (int j = 0; j < 4; j++)
        acc[i][j] = __builtin_amdgcn_mfma_f32_16x16x32_bf16(afrag[i], bfrag[j], acc[i][j], 0, 0, 0);
    __builtin_amdgcn_s_setprio(0);
    asm volatile("" ::: "memory");
  }

  // --- epilogue: silu(g)*u in-register, bf16 store ---
  const int m4 = kg * 4;     // C/D: col = lane&15, row = (lane>>4)*4 + reg
#pragma unroll
  for (int i = 0; i < 8; i++) {
#pragma unroll
    for (int r = 0; r < 4; r++) {
      size_t hbase = (size_t)(row0 + wr * 128 + i * 16 + m4 + r) * FF_DIM;
#pragma unroll
      for (int p = 0; p < 2; p++) {
        float g = acc[i][2 * p][r], u = acc[i][2 * p + 1][r];
        float h = (g / (1.f + __expf(-g))) * u;
        H[hbase + tn * 128 + (wc * 2 + p) * 16 + fr] = f2bf(h);
      }
    }
  }
}

// ---------------- GEMM2: out[tok] = (H @ Wd^T) * topw, fp32 scatter ----------------
__global__ __launch_bounds__(512, 2) void gemm2_kernel(const ushort* __restrict__ Hb,
                                                       const ushort* __restrict__ Wd,
                                                       const int* __restrict__ perm,
                                                       const float* __restrict__ twg,
                                                       float* __restrict__ out,
                                                       const int* __restrict__ ctrl) {
  __shared__ ushort lds[3 * 16384];
  const int ptot = ctrl[C_PTOT];
  const int bid = blockIdx.x;
  const int swz = (bid & 7) * (G2_GRID / 8) + (bid >> 3);   // XCD k owns tn k (B L2-resident)
  const int tn = swz / NMT, bx = swz % NMT;
  const int row0 = bx * 256;
  if (row0 >= ptot) return;
  const int e = (row0 >= ctrl[C_BASE1]) ? 1 : 0;

  const int tid = threadIdx.x, w = tid >> 6, l = tid & 63;
  const int wr = w >> 2, wc = w & 3;
  const int fr = l & 15, kg = l >> 4;

  auto srcptr = [&](int li) -> const ushort* {
    int o = li * 8192 + w * 1024 + l * 16;
    int row = o >> 7, pc = (o >> 4) & 7;
    int lc = pc ^ (row & 7);
    if (lc < 4)
      return Hb + (size_t)(row0 + row) * FF_DIM + lc * 8;
    return Wd + ((size_t)e * D_DIM + tn * 256 + row) * FF_DIM + (lc - 4) * 8;
  };
  const ushort* s0 = srcptr(0);
  const ushort* s1 = srcptr(1);
  const ushort* s2 = srcptr(2);
  const ushort* s3 = srcptr(3);

  auto STAGE = [&](int buf) {
    ushort* db = lds + buf * 16384 + (w << 9);
    gload16(s0, db);          s0 += 32;
    gload16(s1, db + 4096);   s1 += 32;
    gload16(s2, db + 8192);   s2 += 32;
    gload16(s3, db + 12288);  s3 += 32;
  };

  const int aoff = (wr * 128 + fr) * 128 + ((kg ^ (fr & 7)) << 4);
  const int boff = (wc * 64 + fr) * 128 + (((4 ^ kg) ^ (fr & 7)) << 4);

  f32x4 acc[8][4] = {};

  STAGE(0);
  STAGE(1);
  int sbuf = 2, cbuf = 0;
  for (int t = 0; t < NT2; ++t) {
    if (t < NT2 - 1) asm volatile("s_waitcnt vmcnt(4)" ::: "memory");
    else             asm volatile("s_waitcnt vmcnt(0)" ::: "memory");
    __builtin_amdgcn_s_barrier();
    asm volatile("" ::: "memory");
    if (t + 2 < NT2) {
      STAGE(sbuf);
      sbuf = (sbuf == 2) ? 0 : sbuf + 1;
    }
    const char* Lb = (const char*)lds + cbuf * 32768;
    cbuf = (cbuf == 2) ? 0 : cbuf + 1;
    short8 bfrag[4], afrag[8];
#pragma unroll
    for (int j = 0; j < 4; j++) bfrag[j] = *(const short8*)(Lb + boff + j * 2048);
#pragma unroll
    for (int i = 0; i < 8; i++) afrag[i] = *(const short8*)(Lb + aoff + i * 2048);
    __builtin_amdgcn_s_setprio(1);
#pragma unroll
    for (int i = 0; i < 8; i++)
#pragma unroll
      for (int j = 0; j < 4; j++)
        acc[i][j] = __builtin_amdgcn_mfma_f32_16x16x32_bf16(afrag[i], bfrag[j], acc[i][j], 0, 0, 0);
    __builtin_amdgcn_s_setprio(0);
    asm volatile("" ::: "memory");
  }

  const int m4 = kg * 4;
#pragma unroll
  for (int i = 0; i < 8; i++) {
#pragma unroll
    for (int r = 0; r < 4; r++) {
      int prow = row0 + wr * 128 + i * 16 + m4 + r;
      int tok = perm[prow];
      if (tok < 0) continue;               // padding row
      float tw = twg[prow];
      float* orow = out + (size_t)tok * D_DIM + tn * 256 + wc * 64;
#pragma unroll
      for (int j = 0; j < 4; j++) orow[j * 16 + fr] = acc[i][j][r] * tw;
    }
  }
}

// ---------------- launch ----------------
extern "C" void kernel_launch(void* const* d_in, const int* in_sizes, int n_in,
                              void* d_out, int out_size, void* d_ws, size_t ws_size,
                              hipStream_t stream) {
  const float* x  = (const float*)d_in[0];   // [B,S,D] fp32
  const float* gw = (const float*)d_in[1];   // [E,D]
  const float* wg = (const float*)d_in[2];   // [E,FF,D]
  const float* wu = (const float*)d_in[3];   // [E,FF,D]
  const float* wd = (const float*)d_in[4];   // [E,D,FF]
  float* out = (float*)d_out;

  char* ws = (char*)d_ws;
  size_t off = 0;
  auto alloc = [&](size_t bytes) -> void* {
    void* p = ws + off;
    off += (bytes + 255) & ~(size_t)255;
    return p;
  };
  const size_t WELEM = (size_t)2 * FF_DIM * D_DIM;  // 33,554,432 elems per weight tensor
  ushort* Wg_b = (ushort*)alloc(WELEM * 2);
  ushort* Wu_b = (ushort*)alloc(WELEM * 2);
  ushort* Wd_b = (ushort*)alloc(WELEM * 2);
  ushort* Xg   = (ushort*)alloc((size_t)PADT * D_DIM * 2);
  ushort* Hbuf = (ushort*)alloc((size_t)PADT * FF_DIM * 2);
  int*   sel  = (int*)alloc(T_TOK * 4);
  float* topw = (float*)alloc(T_TOK * 4);
  int*   perm = (int*)alloc(PADT * 4);
  float* twg  = (float*)alloc(PADT * 4);
  int*   ctrl = (int*)alloc(256);
  (void)ws_size; (void)in_sizes; (void)n_in; (void)out_size;

  const int n4 = (int)(WELEM / 4);            // 8,388,608 float4 per weight
  cvt3_kernel<<<4096, 256, 0, stream>>>((const float4*)wg, (const float4*)wu,
                                        (const float4*)wd, (ushort4*)Wg_b,
                                        (ushort4*)Wu_b, (ushort4*)Wd_b, n4);

  init_kernel<<<(PADT + 255) / 256, 256, 0, stream>>>(ctrl, perm);
  router_kernel<<<T_TOK / 4, 256, 0, stream>>>(x, gw, sel, topw, ctrl);
  setup_kernel<<<1, 64, 0, stream>>>(ctrl);
  scatter_kernel<<<T_TOK / 256, 256, 0, stream>>>(sel, ctrl, perm);
  gather_kernel<<<PADT / 4, 256, 0, stream>>>(x, perm, topw, Xg, twg);

  gemm1_kernel<<<G1_GRID, 512, 0, stream>>>(Xg, Wg_b, Wu_b, Hbuf, ctrl);
  gemm2_kernel<<<G2_GRID, 512, 0, stream>>>(Hbuf, Wd_b, perm, twg, out, ctrl);
}